// Round 5
// baseline (382.508 us; speedup 1.0000x reference)
//
#include <hip/hip_runtime.h>

// WaveFDTD2D, persistent fenceless-sync kernel + trapezoid 2-step groups (r18).
// r16 (PASSED, 260us dispatch): VALUBusy 21% -> ~1220cy/substep wall vs ~260cy
// VALU issue; ~900cy/substep is barrier convoy + ds_read latency, paid 16x per
// round. r17 (2 blocks/CU restructure) FAILED nondeterministically -> reverted;
// all cross-block machinery here is byte-identical to validated r16.
// r18 change (in-block only): trapezoidal S=2 temporal groups. Per group each
// wave reads a 2-row (cur,old) float2 halo, advances TWO substeps in registers
// (A: 6 intermediate rows; B: 4 own rows, pure-register), writes (t+2, t+1)
// float2, ONE barrier. Per round: 8 group barriers instead of 16 substep
// barriers; ds-latency paid per group. Arithmetic per cell per timestep is
// bit-identical to S=1 (A recomputes halo rows redundantly from the same
// inputs). Contamination: dummy zero rows at ext -2,-1,64,65; penetration 1
// row/substep; interior depth 16 -> safe (same margin as r13-r16). Receivers:
// the float2 write carries BOTH sample times (.y = t0+2g+1, .x = t0+2g+2).
// Source: injected into every redundant register copy (any wave whose A-range
// covers the source row), so copies never diverge.

#define NXd 512
#define NZd 512
#define NSTEPSd 512
#define NRECd 128
#define DT2f 1.0e-6f
#define INVf 1.0e-2f
#define TBk 16
#define TIk 32
#define EXTk 64
#define NTILEk 16
#define PADk 16
#define PWk 544              // NXd + 2*PADk = 16*34
#define LROWS 68             // 2 dummy + 64 ext rows + 2 dummy (float2 rows)
#define NROUNDS (NSTEPSd / TBk)
#define NGRP 8               // 8 groups x 2 substeps = 16 substeps/round

__device__ __forceinline__ float dpp_shr1(float x) {  // lane i <- lane i-1
    int v = __builtin_amdgcn_update_dpp(0, __builtin_bit_cast(int, x),
                                        0x138, 0xF, 0xF, false);  // WAVE_SHR:1
    return __builtin_bit_cast(float, v);
}
__device__ __forceinline__ float dpp_shl1(float x) {  // lane i <- lane i+1
    int v = __builtin_amdgcn_update_dpp(0, __builtin_bit_cast(int, x),
                                        0x130, 0xF, 0xF, false);  // WAVE_SHL:1
    return __builtin_bit_cast(float, v);
}

// Coherent-point (agent-scope) 8B field accesses: bypass L1/L2, hit L3.
__device__ __forceinline__ float2 ldg_f2(const float2* p) {
    unsigned long long v = __hip_atomic_load(
        (const unsigned long long*)p, __ATOMIC_RELAXED, __HIP_MEMORY_SCOPE_AGENT);
    return __builtin_bit_cast(float2, v);
}
__device__ __forceinline__ void stg_f2(float2* p, float2 x) {
    __hip_atomic_store((unsigned long long*)p,
                       __builtin_bit_cast(unsigned long long, x),
                       __ATOMIC_RELAXED, __HIP_MEMORY_SCOPE_AGENT);
}

__global__ __launch_bounds__(1024) void fdtd_persist(
    const float* __restrict__ vel, const float* __restrict__ source,
    const int* __restrict__ src_x, const int* __restrict__ src_z,
    const int* __restrict__ rec_x, const int* __restrict__ rec_z,
    float2* __restrict__ PA, float2* __restrict__ PB,
    float* __restrict__ out, unsigned* __restrict__ done)
{
    // (cur, old) pairs; buffer row = ext row + 2; rows 0,1,66,67 = zero dummies.
    __shared__ float2 sb[2][LROWS * EXTk];

    const int tid = threadIdx.x;
    const int w   = tid >> 6;       // 16 waves, wave w owns ext rows 4w..4w+3
    const int ez  = tid & 63;       // lane -> ext z coord
    const int bx = blockIdx.x, by = blockIdx.y;
    const int gx0 = by * TIk;
    const int gz0 = bx * TIk;
    const int ox = gx0 - TBk, oz = gz0 - TBk;
    const int myid = (by * NTILEk + bx) * 32;   // 128B-strided counter slot

    // ---- Block-local init: zero own 34x34 padded patch of PA and PB ----
    for (int i = tid; i < 34 * 34; i += 1024) {
        const int p = (by * 34 + i / 34) * PWk + (bx * 34 + i % 34);
        stg_f2(&PA[p], make_float2(0.f, 0.f));
        stg_f2(&PB[p], make_float2(0.f, 0.f));
    }

    // O(1) receiver ownership; owning block zeros its receivers' out rows.
    bool rOwn = false; int rIdx = 0;
    if (tid < NRECd) {
        const int rx = rec_x[tid], rz = rec_z[tid];
        rOwn = (rx >= gx0 && rx < gx0 + TIk && rz >= gz0 && rz < gz0 + TIk);
        rIdx = (rx - ox + 2) * EXTk + (rz - oz);    // float2 buffer index
        if (rOwn) {
            float4* o4 = (float4*)&out[tid * NSTEPSd];
            #pragma unroll
            for (int j = 0; j < NSTEPSd / 4; ++j) o4[j] = make_float4(0.f, 0.f, 0.f, 0.f);
        }
    }

    // V2 for the 6 A-rows (ext rows 4w-1 .. 4w+4): v^2*dt^2/(dx*dz), 0 in apron.
    float rV2x[6];
    {
        const int fz = oz + ez;
        #pragma unroll
        for (int j = 0; j < 6; ++j) {
            const int fx = ox + 4 * w - 1 + j;
            float v2 = 0.f;
            if (fx >= 0 && fx < NXd && fz >= 0 && fz < NZd) {
                float v = vel[fx * NZd + fz];
                v2 = v * v * (DT2f * INVf);
            }
            rV2x[j] = v2;
        }
    }

    // Dummy rows (ext -2,-1,64,65 = buffer 0,1,66,67), both buffers, zero forever.
    if (w == 0) {
        #pragma unroll
        for (int b = 0; b < 2; ++b) {
            sb[b][0 * EXTk + ez]  = make_float2(0.f, 0.f);
            sb[b][1 * EXTk + ez]  = make_float2(0.f, 0.f);
            sb[b][66 * EXTk + ez] = make_float2(0.f, 0.f);
            sb[b][67 * EXTk + ez] = make_float2(0.f, 0.f);
        }
    }

    // Source: every wave whose A-range (ext rows 4w-1..4w+4) covers the source
    // row injects into its own register copy (redundant copies stay identical).
    const int sx = *src_x, sz = *src_z;
    const int exs = sx - ox, ezs = sz - oz;
    const int jA0 = exs - (4 * w - 1);           // A-slot of source row
    const bool svTouch = (ez == ezs) && (jA0 >= 0) && (jA0 < 6);

    // Exact L1 cone: active at round k iff dman <= 16k+17.
    const int dxm = max(0, max(ox - sx, sx - (ox + EXTk - 1)));
    const int dzm = max(0, max(oz - sz, sz - (oz + EXTk - 1)));
    const int dman = dxm + dzm;
    const int kAct = dman <= (TBk + 1) ? 0 : (dman - (TBk + 1) + TBk - 1) / TBk;

    // Counter slot of each of my 8 neighbors (clamped; clamp->self benign).
    int nb = myid;
    if (tid < 8) {
        const int d = (tid < 4) ? tid : tid + 1;          // skip center
        const int ny = min(NTILEk - 1, max(0, by + d / 3 - 1));
        const int nx = min(NTILEk - 1, max(0, bx + d % 3 - 1));
        nb = (ny * NTILEk + nx) * 32;
    }

    const int pbase = (gx0 + 4 * w) * PWk + gz0 + ez;  // padded global index
    const int rd0 = (4 * w) * EXTk + ez;   // buffer row 4w = ext row 4w-2

    // Publish init + entire cone-skipped prefix in one store (vmcnt drained
    // by the barrier; agent stores are visible at the coherence point).
    __syncthreads();
    if (tid == 0)
        __hip_atomic_store(&done[myid], (unsigned)(kAct + 1),
                           __ATOMIC_RELAXED, __HIP_MEMORY_SCOPE_AGENT);

    // ---- Rounds kAct..31; monotone cone => always active once started ----
    for (int k = kAct; k < NROUNDS; ++k) {
        const int t0 = TBk * k;

        // Wait: 8 neighbors finished round k-1 (reads AND writes).
        if (tid < 8) {
            const unsigned tgt = (unsigned)(k + 1);
            while (__hip_atomic_load(&done[nb], __ATOMIC_RELAXED,
                                     __HIP_MEMORY_SCOPE_AGENT) < tgt)
                __builtin_amdgcn_s_sleep(1);
        }
        __syncthreads();

        float2* __restrict__ Pin  = (k & 1) ? PB : PA;
        float2* __restrict__ Pout = (k & 1) ? PA : PB;

        // Unconditional padded agent loads (apron = zeros forever).
        float2 co[4];
        #pragma unroll
        for (int i = 0; i < 4; ++i) co[i] = ldg_f2(&Pin[pbase + i * PWk]);

        // Unpack + prefill LDS buffer 0 (own rows, (cur,old) pairs).
        float rCur[4], rOld[4];
        #pragma unroll
        for (int i = 0; i < 4; ++i) {
            rCur[i] = co[i].x; rOld[i] = co[i].y;
            sb[0][(4 * w + 2 + i) * EXTk + ez] = co[i];
        }

        float sv[TBk];
        if (svTouch) {
            #pragma unroll
            for (int s = 0; s < TBk; ++s) sv[s] = source[t0 + s] * DT2f;
        }

        __syncthreads();

        // ---- 8 trapezoid groups, 2 substeps each, fully unrolled ----
        float rv[TBk];
        #pragma unroll
        for (int g = 0; g < NGRP; ++g) {
            const float2* cur = sb[g & 1];
            float2* nxt = sb[(g & 1) ^ 1];
            // Halo (cur,old) rows: ext 4w-2, 4w-1, 4w+4, 4w+5.
            const float2 h0 = cur[rd0];
            const float2 h1 = cur[rd0 + EXTk];
            const float2 h4 = cur[rd0 + 6 * EXTk];
            const float2 h5 = cur[rd0 + 7 * EXTk];
            const float curv[8] = {h0.x, h1.x, rCur[0], rCur[1],
                                   rCur[2], rCur[3], h4.x, h5.x};
            const float oldA[6] = {h1.y, rOld[0], rOld[1],
                                   rOld[2], rOld[3], h4.y};
            // Substep A: 6 rows (ext 4w-1 .. 4w+4), time t0+2g -> t0+2g+1.
            float cA[6];
            #pragma unroll
            for (int j = 0; j < 6; ++j) {
                const float c = curv[j + 1];
                const float sum = (curv[j] + curv[j + 2]) +
                                  (dpp_shr1(c) + dpp_shl1(c));
                cA[j] = __builtin_fmaf(rV2x[j], __builtin_fmaf(-4.0f, c, sum),
                                       __builtin_fmaf(2.0f, c, -oldA[j]));
            }
            #pragma unroll
            for (int j = 0; j < 6; ++j)
                if (j == jA0 && svTouch) cA[j] += sv[2 * g];
            // Substep B: 4 own rows, pure-register, time -> t0+2g+2.
            float cB[4];
            #pragma unroll
            for (int i = 0; i < 4; ++i) {
                const float c = cA[i + 1];
                const float sum = (cA[i] + cA[i + 2]) +
                                  (dpp_shr1(c) + dpp_shl1(c));
                cB[i] = __builtin_fmaf(rV2x[i + 1], __builtin_fmaf(-4.0f, c, sum),
                                       __builtin_fmaf(2.0f, c, -rCur[i]));
            }
            #pragma unroll
            for (int i = 0; i < 4; ++i)
                if (i + 1 == jA0 && svTouch) cB[i] += sv[2 * g + 1];
            // Commit: registers + LDS (cur=t+2, old=t+1), one barrier.
            #pragma unroll
            for (int i = 0; i < 4; ++i) {
                rOld[i] = cA[i + 1];
                rCur[i] = cB[i];
                nxt[(4 * w + 2 + i) * EXTk + ez] = make_float2(cB[i], cA[i + 1]);
            }
            __syncthreads();
            // Receiver: one float2 read yields BOTH sample times of the group.
            // Next group writes the OTHER buffer; the group-after-next's write
            // to this buffer is fenced by the next barrier -> race-free.
            if (rOwn) {
                const float2 rr = nxt[rIdx];
                rv[2 * g]     = rr.y;   // time t0+2g+1
                rv[2 * g + 1] = rr.x;   // time t0+2g+2
            }
        }

        // Store interior (ext rows 16..47 = waves 4..11, ez 16..47).
        if (w >= 4 && w < 12 && ez >= TBk && ez < EXTk - TBk) {
            #pragma unroll
            for (int i = 0; i < 4; ++i)
                stg_f2(&Pout[pbase + i * PWk], make_float2(rCur[i], rOld[i]));
        }

        // Flush receiver buffer (block-private, normal stores).
        if (rOwn) {
            #pragma unroll
            for (int s = 0; s < TBk; ++s)
                out[tid * NSTEPSd + t0 + s] = rv[s];
        }

        // Publish round k. __syncthreads drains every wave's vmcnt (all
        // agent-store acks) before tid 0 can issue the counter store.
        __syncthreads();
        if (tid == 0)
            __hip_atomic_store(&done[myid], (unsigned)(k + 2),
                               __ATOMIC_RELAXED, __HIP_MEMORY_SCOPE_AGENT);
    }
}

extern "C" void kernel_launch(void* const* d_in, const int* in_sizes, int n_in,
                              void* d_out, int out_size, void* d_ws, size_t ws_size,
                              hipStream_t stream) {
    const float* vel    = (const float*)d_in[0];
    const float* source = (const float*)d_in[1];
    const int*   src_x  = (const int*)d_in[2];
    const int*   src_z  = (const int*)d_in[3];
    const int*   rec_x  = (const int*)d_in[4];
    const int*   rec_z  = (const int*)d_in[5];
    float* out = (float*)d_out;

    const size_t FP = (size_t)PWk * PWk;
    float2* PA = (float2*)d_ws;       // padded (cur, old), set A
    float2* PB = PA + FP;             // set B
    unsigned* DONE = (unsigned*)(PB + FP);   // 256 counters, 128B stride

    hipMemsetAsync(DONE, 0, (size_t)NTILEk * NTILEk * 32 * sizeof(unsigned), stream);

    void* args[] = {(void*)&vel, (void*)&source, (void*)&src_x, (void*)&src_z,
                    (void*)&rec_x, (void*)&rec_z, (void*)&PA, (void*)&PB,
                    (void*)&out, (void*)&DONE};
    hipLaunchCooperativeKernel((void*)fdtd_persist, dim3(NTILEk, NTILEk),
                               dim3(1024), args, 0, stream);
}

// Round 6
// 366.854 us; speedup vs baseline: 1.0427x; 1.0427x over previous
//
#include <hip/hip_runtime.h>

// WaveFDTD2D, persistent fenceless-sync kernel + SoA trapezoid groups (r19).
// r16 (260us): S=1, float LDS, 336 bank conflicts. r18 (301us): S=2 trapezoid
// with float2 LDS -> SQ_LDS_BANK_CONFLICT 1.73M (b64 accesses conflict) and
// +25% VALU; barrier halving bought ~0 (barriers are cheap -- falsified).
// r19: keep r18's VALIDATED trapezoid math + r16's VALIDATED protocol, but
// SoA LDS: separate float scur[2]/sold[2] arrays; every access is 4B
// stride-1 (conflict-free). Halo reads pair as ds_read2st64_b32, commits as
// ds_write2st64_b32: 3 read + 4 write LDS instrs per group (vs r16's ~6 per
// substep), half the read-latency exposures per 2 substeps, zero conflicts.
// Per group each wave: reads cur halo rows 4w-2,4w-1,4w+4,4w+5 + old halo
// rows 4w-1,4w+4; substep A updates 6 rows (ext 4w-1..4w+4) t->t+1; substep
// B updates own 4 rows t+1->t+2 pure-register; commits (t+2 -> scur,
// t+1 -> sold), ONE barrier. Arithmetic per cell per timestep bit-identical
// to S=1 (halo rows recomputed redundantly from identical inputs).
// Contamination: dummy zero rows ext -2,-1,64,65; 1 row/substep penetration;
// interior depth 16 -> safe. Receiver float pair (scur=t+2, sold=t+1) read
// after the barrier; next group writes the other buffer -> race-free.
// Source injected into every redundant register copy (waves whose A-range
// covers the source row), so copies never diverge.

#define NXd 512
#define NZd 512
#define NSTEPSd 512
#define NRECd 128
#define DT2f 1.0e-6f
#define INVf 1.0e-2f
#define TBk 16
#define TIk 32
#define EXTk 64
#define NTILEk 16
#define PADk 16
#define PWk 544              // NXd + 2*PADk = 16*34
#define LROWS 68             // 2 dummy + 64 ext rows + 2 dummy
#define NROUNDS (NSTEPSd / TBk)
#define NGRP 8               // 8 groups x 2 substeps = 16 substeps/round

__device__ __forceinline__ float dpp_shr1(float x) {  // lane i <- lane i-1
    int v = __builtin_amdgcn_update_dpp(0, __builtin_bit_cast(int, x),
                                        0x138, 0xF, 0xF, false);  // WAVE_SHR:1
    return __builtin_bit_cast(float, v);
}
__device__ __forceinline__ float dpp_shl1(float x) {  // lane i <- lane i+1
    int v = __builtin_amdgcn_update_dpp(0, __builtin_bit_cast(int, x),
                                        0x130, 0xF, 0xF, false);  // WAVE_SHL:1
    return __builtin_bit_cast(float, v);
}

// Coherent-point (agent-scope) 8B field accesses: bypass L1/L2, hit L3.
__device__ __forceinline__ float2 ldg_f2(const float2* p) {
    unsigned long long v = __hip_atomic_load(
        (const unsigned long long*)p, __ATOMIC_RELAXED, __HIP_MEMORY_SCOPE_AGENT);
    return __builtin_bit_cast(float2, v);
}
__device__ __forceinline__ void stg_f2(float2* p, float2 x) {
    __hip_atomic_store((unsigned long long*)p,
                       __builtin_bit_cast(unsigned long long, x),
                       __ATOMIC_RELAXED, __HIP_MEMORY_SCOPE_AGENT);
}

__global__ __launch_bounds__(1024) void fdtd_persist(
    const float* __restrict__ vel, const float* __restrict__ source,
    const int* __restrict__ src_x, const int* __restrict__ src_z,
    const int* __restrict__ rec_x, const int* __restrict__ rec_z,
    float2* __restrict__ PA, float2* __restrict__ PB,
    float* __restrict__ out, unsigned* __restrict__ done)
{
    // SoA: cur and old in separate float arrays; buffer row = ext row + 2;
    // rows 0,1,66,67 are zero dummies. All accesses 4B stride-1.
    __shared__ float scur[2][LROWS * EXTk];
    __shared__ float sold[2][LROWS * EXTk];

    const int tid = threadIdx.x;
    const int w   = tid >> 6;       // 16 waves, wave w owns ext rows 4w..4w+3
    const int ez  = tid & 63;       // lane -> ext z coord
    const int bx = blockIdx.x, by = blockIdx.y;
    const int gx0 = by * TIk;
    const int gz0 = bx * TIk;
    const int ox = gx0 - TBk, oz = gz0 - TBk;
    const int myid = (by * NTILEk + bx) * 32;   // 128B-strided counter slot

    // ---- Block-local init: zero own 34x34 padded patch of PA and PB ----
    for (int i = tid; i < 34 * 34; i += 1024) {
        const int p = (by * 34 + i / 34) * PWk + (bx * 34 + i % 34);
        stg_f2(&PA[p], make_float2(0.f, 0.f));
        stg_f2(&PB[p], make_float2(0.f, 0.f));
    }

    // O(1) receiver ownership; owning block zeros its receivers' out rows.
    bool rOwn = false; int rIdx = 0;
    if (tid < NRECd) {
        const int rx = rec_x[tid], rz = rec_z[tid];
        rOwn = (rx >= gx0 && rx < gx0 + TIk && rz >= gz0 && rz < gz0 + TIk);
        rIdx = (rx - ox + 2) * EXTk + (rz - oz);    // buffer index (row+2)
        if (rOwn) {
            float4* o4 = (float4*)&out[tid * NSTEPSd];
            #pragma unroll
            for (int j = 0; j < NSTEPSd / 4; ++j) o4[j] = make_float4(0.f, 0.f, 0.f, 0.f);
        }
    }

    // V2 for the 6 A-rows (ext rows 4w-1 .. 4w+4): v^2*dt^2/(dx*dz), 0 in apron.
    float rV2x[6];
    {
        const int fz = oz + ez;
        #pragma unroll
        for (int j = 0; j < 6; ++j) {
            const int fx = ox + 4 * w - 1 + j;
            float v2 = 0.f;
            if (fx >= 0 && fx < NXd && fz >= 0 && fz < NZd) {
                float v = vel[fx * NZd + fz];
                v2 = v * v * (DT2f * INVf);
            }
            rV2x[j] = v2;
        }
    }

    // Dummy rows (ext -2,-1,64,65 = buffer 0,1,66,67), both buffers, both
    // arrays, zero forever.
    if (w == 0) {
        #pragma unroll
        for (int b = 0; b < 2; ++b) {
            scur[b][0 * EXTk + ez]  = 0.f;  sold[b][0 * EXTk + ez]  = 0.f;
            scur[b][1 * EXTk + ez]  = 0.f;  sold[b][1 * EXTk + ez]  = 0.f;
            scur[b][66 * EXTk + ez] = 0.f;  sold[b][66 * EXTk + ez] = 0.f;
            scur[b][67 * EXTk + ez] = 0.f;  sold[b][67 * EXTk + ez] = 0.f;
        }
    }

    // Source: every wave whose A-range (ext rows 4w-1..4w+4) covers the source
    // row injects into its own register copy (redundant copies stay identical).
    const int sx = *src_x, sz = *src_z;
    const int exs = sx - ox, ezs = sz - oz;
    const int jA0 = exs - (4 * w - 1);           // A-slot of source row
    const bool svTouch = (ez == ezs) && (jA0 >= 0) && (jA0 < 6);

    // Exact L1 cone: active at round k iff dman <= 16k+17.
    const int dxm = max(0, max(ox - sx, sx - (ox + EXTk - 1)));
    const int dzm = max(0, max(oz - sz, sz - (oz + EXTk - 1)));
    const int dman = dxm + dzm;
    const int kAct = dman <= (TBk + 1) ? 0 : (dman - (TBk + 1) + TBk - 1) / TBk;

    // Counter slot of each of my 8 neighbors (clamped; clamp->self benign).
    int nb = myid;
    if (tid < 8) {
        const int d = (tid < 4) ? tid : tid + 1;          // skip center
        const int ny = min(NTILEk - 1, max(0, by + d / 3 - 1));
        const int nx = min(NTILEk - 1, max(0, bx + d % 3 - 1));
        nb = (ny * NTILEk + nx) * 32;
    }

    const int pbase = (gx0 + 4 * w) * PWk + gz0 + ez;  // padded global index
    const int rd0 = (4 * w) * EXTk + ez;   // buffer row 4w = ext row 4w-2

    // Publish init + entire cone-skipped prefix in one store (vmcnt drained
    // by the barrier; agent stores are visible at the coherence point).
    __syncthreads();
    if (tid == 0)
        __hip_atomic_store(&done[myid], (unsigned)(kAct + 1),
                           __ATOMIC_RELAXED, __HIP_MEMORY_SCOPE_AGENT);

    // ---- Rounds kAct..31; monotone cone => always active once started ----
    for (int k = kAct; k < NROUNDS; ++k) {
        const int t0 = TBk * k;

        // Wait: 8 neighbors finished round k-1 (reads AND writes).
        if (tid < 8) {
            const unsigned tgt = (unsigned)(k + 1);
            while (__hip_atomic_load(&done[nb], __ATOMIC_RELAXED,
                                     __HIP_MEMORY_SCOPE_AGENT) < tgt)
                __builtin_amdgcn_s_sleep(1);
        }
        __syncthreads();

        float2* __restrict__ Pin  = (k & 1) ? PB : PA;
        float2* __restrict__ Pout = (k & 1) ? PA : PB;

        // Unconditional padded agent loads (apron = zeros forever).
        float2 co[4];
        #pragma unroll
        for (int i = 0; i < 4; ++i) co[i] = ldg_f2(&Pin[pbase + i * PWk]);

        // Unpack + prefill LDS buffer 0 (own rows).
        float rCur[4], rOld[4];
        #pragma unroll
        for (int i = 0; i < 4; ++i) {
            rCur[i] = co[i].x; rOld[i] = co[i].y;
            scur[0][(4 * w + 2 + i) * EXTk + ez] = co[i].x;
            sold[0][(4 * w + 2 + i) * EXTk + ez] = co[i].y;
        }

        float sv[TBk];
        if (svTouch) {
            #pragma unroll
            for (int s = 0; s < TBk; ++s) sv[s] = source[t0 + s] * DT2f;
        }

        __syncthreads();

        // ---- 8 trapezoid groups, 2 substeps each, fully unrolled ----
        float rv[TBk];
        #pragma unroll
        for (int g = 0; g < NGRP; ++g) {
            const float* sc  = scur[g & 1];
            const float* so  = sold[g & 1];
            float* nc = scur[(g & 1) ^ 1];
            float* no = sold[(g & 1) ^ 1];
            // Halo rows (stride-1 b32; pairs -> ds_read2st64_b32):
            // cur: ext 4w-2, 4w-1, 4w+4, 4w+5;  old: ext 4w-1, 4w+4.
            const float c_m2 = sc[rd0];
            const float c_m1 = sc[rd0 + EXTk];
            const float c_p4 = sc[rd0 + 6 * EXTk];
            const float c_p5 = sc[rd0 + 7 * EXTk];
            const float o_m1 = so[rd0 + EXTk];
            const float o_p4 = so[rd0 + 6 * EXTk];
            const float curv[8] = {c_m2, c_m1, rCur[0], rCur[1],
                                   rCur[2], rCur[3], c_p4, c_p5};
            const float oldA[6] = {o_m1, rOld[0], rOld[1],
                                   rOld[2], rOld[3], o_p4};
            // Substep A: 6 rows (ext 4w-1 .. 4w+4), time t0+2g -> t0+2g+1.
            float cA[6];
            #pragma unroll
            for (int j = 0; j < 6; ++j) {
                const float c = curv[j + 1];
                const float sum = (curv[j] + curv[j + 2]) +
                                  (dpp_shr1(c) + dpp_shl1(c));
                cA[j] = __builtin_fmaf(rV2x[j], __builtin_fmaf(-4.0f, c, sum),
                                       __builtin_fmaf(2.0f, c, -oldA[j]));
            }
            #pragma unroll
            for (int j = 0; j < 6; ++j)
                if (j == jA0 && svTouch) cA[j] += sv[2 * g];
            // Substep B: 4 own rows, pure-register, time -> t0+2g+2.
            float cB[4];
            #pragma unroll
            for (int i = 0; i < 4; ++i) {
                const float c = cA[i + 1];
                const float sum = (cA[i] + cA[i + 2]) +
                                  (dpp_shr1(c) + dpp_shl1(c));
                cB[i] = __builtin_fmaf(rV2x[i + 1], __builtin_fmaf(-4.0f, c, sum),
                                       __builtin_fmaf(2.0f, c, -rCur[i]));
            }
            #pragma unroll
            for (int i = 0; i < 4; ++i)
                if (i + 1 == jA0 && svTouch) cB[i] += sv[2 * g + 1];
            // Commit: registers + LDS (scur=t+2, sold=t+1), one barrier.
            // Pairs -> ds_write2st64_b32, stride-1 b32, conflict-free.
            #pragma unroll
            for (int i = 0; i < 4; ++i) {
                rOld[i] = cA[i + 1];
                rCur[i] = cB[i];
                nc[(4 * w + 2 + i) * EXTk + ez] = cB[i];
                no[(4 * w + 2 + i) * EXTk + ez] = cA[i + 1];
            }
            __syncthreads();
            // Receiver: both sample times of the group. Next group writes the
            // OTHER buffer; the write-after that is fenced by the next barrier.
            if (rOwn) {
                rv[2 * g]     = no[rIdx];   // time t0+2g+1
                rv[2 * g + 1] = nc[rIdx];   // time t0+2g+2
            }
        }

        // Store interior (ext rows 16..47 = waves 4..11, ez 16..47).
        if (w >= 4 && w < 12 && ez >= TBk && ez < EXTk - TBk) {
            #pragma unroll
            for (int i = 0; i < 4; ++i)
                stg_f2(&Pout[pbase + i * PWk], make_float2(rCur[i], rOld[i]));
        }

        // Flush receiver buffer (block-private, normal stores).
        if (rOwn) {
            #pragma unroll
            for (int s = 0; s < TBk; ++s)
                out[tid * NSTEPSd + t0 + s] = rv[s];
        }

        // Publish round k. __syncthreads drains every wave's vmcnt (all
        // agent-store acks) before tid 0 can issue the counter store.
        __syncthreads();
        if (tid == 0)
            __hip_atomic_store(&done[myid], (unsigned)(k + 2),
                               __ATOMIC_RELAXED, __HIP_MEMORY_SCOPE_AGENT);
    }
}

extern "C" void kernel_launch(void* const* d_in, const int* in_sizes, int n_in,
                              void* d_out, int out_size, void* d_ws, size_t ws_size,
                              hipStream_t stream) {
    const float* vel    = (const float*)d_in[0];
    const float* source = (const float*)d_in[1];
    const int*   src_x  = (const int*)d_in[2];
    const int*   src_z  = (const int*)d_in[3];
    const int*   rec_x  = (const int*)d_in[4];
    const int*   rec_z  = (const int*)d_in[5];
    float* out = (float*)d_out;

    const size_t FP = (size_t)PWk * PWk;
    float2* PA = (float2*)d_ws;       // padded (cur, old), set A
    float2* PB = PA + FP;             // set B
    unsigned* DONE = (unsigned*)(PB + FP);   // 256 counters, 128B stride

    hipMemsetAsync(DONE, 0, (size_t)NTILEk * NTILEk * 32 * sizeof(unsigned), stream);

    void* args[] = {(void*)&vel, (void*)&source, (void*)&src_x, (void*)&src_z,
                    (void*)&rec_x, (void*)&rec_z, (void*)&PA, (void*)&PB,
                    (void*)&out, (void*)&DONE};
    hipLaunchCooperativeKernel((void*)fdtd_persist, dim3(NTILEk, NTILEk),
                               dim3(1024), args, 0, stream);
}

// Round 8
// 338.354 us; speedup vs baseline: 1.1305x; 1.0842x over previous
//
#include <hip/hip_runtime.h>

// WaveFDTD2D, persistent fenceless-sync kernel, protocol-trimmed (r20b).
// r20 failed to COMPILE only: s_sleep needs a constant-int literal. Fixed by
// branching to two constant sleeps. Logic otherwise identical to r20:
// Lineage: r16 = validated 260us structure (S=1, 16 waves x 4 rows, DPP
// z-neighbors, LDS x-halo, agent-scope coherent-point field exchange,
// 8-neighbor counter sync). r18/r19 proved the trapezoid family loses
// (transition cost ~0.1us each < S=2 VALU premium) and that the compiled
// stencil VALU is already minimal. r20 = r16 with protocol overhead cuts:
//  1. ALL-WAVE POLLING: lanes 0-7 of every wave poll the 8 neighbor
//     counters -> post-poll barrier and wave-0 funnel removed. Internal
//     LDS safety: the pre-publish barrier serializes rounds block-wide.
//  2. NO PREFILL: substep 0 reads its x-halo (cur of ext rows 4w-1, 4w+4)
//     straight from global (2 extra agent loads); LDS buffer 0 never
//     pre-filled; prefill barrier deleted. Garbage at ext rows -1/64 is
//     tolerable exactly like r16's zero dummies: apron rows have v2=0
//     (update-invariant), non-apron rim rows are contamination-budgeted
//     (1 row/substep, interior depth 16). Guard rows in the workspace
//     keep edge-block reads inside the allocation.
//  3. Receiver out-flush AFTER publish (block-private, off critical path).
//  4. Two-level s_sleep in the poll loop (less L3 traffic during ramp).
// Everything else byte-identical to r16.

#define NXd 512
#define NZd 512
#define NSTEPSd 512
#define NRECd 128
#define DT2f 1.0e-6f
#define INVf 1.0e-2f
#define TBk 16
#define TIk 32
#define EXTk 64
#define NTILEk 16
#define PADk 16
#define PWk 544              // NXd + 2*PADk = 16*34
#define LROWS 66             // 1 dummy + 64 ext rows + 1 dummy
#define NROUNDS (NSTEPSd / TBk)

__device__ __forceinline__ float dpp_shr1(float x) {  // lane i <- lane i-1
    int v = __builtin_amdgcn_update_dpp(0, __builtin_bit_cast(int, x),
                                        0x138, 0xF, 0xF, false);  // WAVE_SHR:1
    return __builtin_bit_cast(float, v);
}
__device__ __forceinline__ float dpp_shl1(float x) {  // lane i <- lane i+1
    int v = __builtin_amdgcn_update_dpp(0, __builtin_bit_cast(int, x),
                                        0x130, 0xF, 0xF, false);  // WAVE_SHL:1
    return __builtin_bit_cast(float, v);
}

// Coherent-point (agent-scope) field accesses: bypass L1/L2, hit L3.
__device__ __forceinline__ float2 ldg_f2(const float2* p) {
    unsigned long long v = __hip_atomic_load(
        (const unsigned long long*)p, __ATOMIC_RELAXED, __HIP_MEMORY_SCOPE_AGENT);
    return __builtin_bit_cast(float2, v);
}
__device__ __forceinline__ float ldg_f1(const float* p) {
    unsigned v = __hip_atomic_load(
        (const unsigned*)p, __ATOMIC_RELAXED, __HIP_MEMORY_SCOPE_AGENT);
    return __builtin_bit_cast(float, v);
}
__device__ __forceinline__ void stg_f2(float2* p, float2 x) {
    __hip_atomic_store((unsigned long long*)p,
                       __builtin_bit_cast(unsigned long long, x),
                       __ATOMIC_RELAXED, __HIP_MEMORY_SCOPE_AGENT);
}

__global__ __launch_bounds__(1024) void fdtd_persist(
    const float* __restrict__ vel, const float* __restrict__ source,
    const int* __restrict__ src_x, const int* __restrict__ src_z,
    const int* __restrict__ rec_x, const int* __restrict__ rec_z,
    float2* __restrict__ PA, float2* __restrict__ PB,
    float* __restrict__ out, unsigned* __restrict__ done)
{
    __shared__ float sb[2][LROWS * EXTk];

    const int tid = threadIdx.x;
    const int w   = tid >> 6;       // 16 waves, wave w owns ext rows 4w..4w+3
    const int ez  = tid & 63;       // lane -> ext z coord
    const int bx = blockIdx.x, by = blockIdx.y;
    const int gx0 = by * TIk;
    const int gz0 = bx * TIk;
    const int ox = gx0 - TBk, oz = gz0 - TBk;
    const int myid = (by * NTILEk + bx) * 32;   // 128B-strided counter slot

    // ---- Block-local init: zero own 34x34 padded patch of PA and PB ----
    for (int i = tid; i < 34 * 34; i += 1024) {
        const int p = (by * 34 + i / 34) * PWk + (bx * 34 + i % 34);
        stg_f2(&PA[p], make_float2(0.f, 0.f));
        stg_f2(&PB[p], make_float2(0.f, 0.f));
    }

    // O(1) receiver ownership; owning block zeros its receivers' out rows.
    bool rOwn = false; int rIdx = 0;
    if (tid < NRECd) {
        const int rx = rec_x[tid], rz = rec_z[tid];
        rOwn = (rx >= gx0 && rx < gx0 + TIk && rz >= gz0 && rz < gz0 + TIk);
        rIdx = (rx - ox + 1) * EXTk + (rz - oz);    // buffer row = ext row + 1
        if (rOwn) {
            float4* o4 = (float4*)&out[tid * NSTEPSd];
            #pragma unroll
            for (int j = 0; j < NSTEPSd / 4; ++j) o4[j] = make_float4(0.f, 0.f, 0.f, 0.f);
        }
    }

    // V2 in 4 registers per thread for the whole run: v^2*dt^2/(dx*dz),
    // 0 in the apron (zero BC) -- never touches global memory.
    float rV2i[4];
    {
        const int fz = oz + ez;
        #pragma unroll
        for (int i = 0; i < 4; ++i) {
            const int fx = ox + 4 * w + i;
            float v2 = 0.f;
            if (fx >= 0 && fx < NXd && fz >= 0 && fz < NZd) {
                float v = vel[fx * NZd + fz];
                v2 = v * v * (DT2f * INVf);
            }
            rV2i[i] = v2;
        }
    }

    // Dummy LDS rows (0 and 65) zero in BOTH buffers; never rewritten.
    if (w == 0) {
        sb[0][ez] = 0.f;
        sb[0][(LROWS - 1) * EXTk + ez] = 0.f;
        sb[1][ez] = 0.f;
        sb[1][(LROWS - 1) * EXTk + ez] = 0.f;
    }

    // Source ownership (owner = lane ezs of wave exs>>2, register exs&3).
    const int sx = *src_x, sz = *src_z;
    const int exs = sx - ox, ezs = sz - oz;
    const bool srcHere = (exs >= 0 && exs < EXTk && ezs >= 0 && ezs < EXTk) &&
                         (tid == (((exs >> 2) << 6) | ezs));

    // Exact L1 cone: active at round k iff dman <= 16k+17.
    const int dxm = max(0, max(ox - sx, sx - (ox + EXTk - 1)));
    const int dzm = max(0, max(oz - sz, sz - (oz + EXTk - 1)));
    const int dman = dxm + dzm;
    const int kAct = dman <= (TBk + 1) ? 0 : (dman - (TBk + 1) + TBk - 1) / TBk;

    // Every wave polls: lanes 0-7 of each wave watch the 8 neighbors
    // (clamped; clamp->self benign: own counter == k+1 entering round k).
    const int lane = tid & 63;
    int nb = myid;
    if (lane < 8) {
        const int d = (lane < 4) ? lane : lane + 1;       // skip center
        const int ny = min(NTILEk - 1, max(0, by + d / 3 - 1));
        const int nx = min(NTILEk - 1, max(0, bx + d % 3 - 1));
        nb = (ny * NTILEk + nx) * 32;
    }

    const int pbase = (gx0 + 4 * w) * PWk + gz0 + ez;  // padded global index
    const int fbase = 4 * w * EXTk + ez;   // buffer row 4w (ext row 4w-1)

    // Publish init + entire cone-skipped prefix in one release store
    // (barrier drains every wave's vmcnt; agent stores visible at L3).
    __syncthreads();
    if (tid == 0)
        __hip_atomic_store(&done[myid], (unsigned)(kAct + 1),
                           __ATOMIC_RELAXED, __HIP_MEMORY_SCOPE_AGENT);

    // ---- Rounds kAct..31; monotone cone => always active once started ----
    for (int k = kAct; k < NROUNDS; ++k) {
        const int t0 = TBk * k;

        // Per-wave wait: 8 neighbors finished round k-1 (reads AND writes).
        // No barrier after: each wave independently gates its own loads;
        // LDS hazards are covered by the pre-publish barrier of round k-1.
        if (lane < 8) {
            const unsigned tgt = (unsigned)(k + 1);
            for (;;) {
                unsigned seen = __hip_atomic_load(&done[nb], __ATOMIC_RELAXED,
                                                  __HIP_MEMORY_SCOPE_AGENT);
                if (seen >= tgt) break;
                if (seen + 1 < tgt) __builtin_amdgcn_s_sleep(16);
                else                __builtin_amdgcn_s_sleep(1);
            }
        }

        float2* __restrict__ Pin  = (k & 1) ? PB : PA;
        float2* __restrict__ Pout = (k & 1) ? PA : PB;

        // Unconditional padded agent loads (apron zeros / tolerated rim).
        float2 co[4];
        #pragma unroll
        for (int i = 0; i < 4; ++i) co[i] = ldg_f2(&Pin[pbase + i * PWk]);
        // Substep-0 x-halo direct from global: cur of ext rows 4w-1, 4w+4.
        // Edge blocks read guard rows (allocated; values tolerated).
        const float huG = ldg_f1((const float*)&Pin[pbase - PWk]);
        const float hdG = ldg_f1((const float*)&Pin[pbase + 4 * PWk]);

        float rCur[4], rOld[4];
        #pragma unroll
        for (int i = 0; i < 4; ++i) { rCur[i] = co[i].x; rOld[i] = co[i].y; }

        float sv[TBk];
        if (srcHere) {
            #pragma unroll
            for (int s = 0; s < TBk; ++s) sv[s] = source[t0 + s] * DT2f;
        }

        // ---- 16 sub-steps, fully unrolled; s=0 uses global halo ----
        float rv[TBk];
        #pragma unroll
        for (int s = 0; s < TBk; ++s) {
            const float* cur = sb[s & 1];
            float* nxt = sb[(s & 1) ^ 1];
            // x-halo: s=0 from global regs; s>=1 wave-uniform ds_read2st64
            // (ext rows 4w-1, 4w+4; edge waves hit zero dummies).
            const float up0 = (s == 0) ? huG : cur[fbase];
            const float dn3 = (s == 0) ? hdG : cur[fbase + 5 * EXTk];
            float nv[4];
            #pragma unroll
            for (int i = 0; i < 4; ++i) {
                const float up = (i == 0) ? up0 : rCur[i - 1];
                const float dn = (i == 3) ? dn3 : rCur[i + 1];
                const float lf = dpp_shr1(rCur[i]);     // z-1 neighbor
                const float rt = dpp_shl1(rCur[i]);     // z+1 neighbor
                const float sum = (up + dn) + (lf + rt);
                const float t4 = __builtin_fmaf(-4.0f, rCur[i], sum);
                const float pm = __builtin_fmaf(2.0f, rCur[i], -rOld[i]);
                nv[i] = __builtin_fmaf(rV2i[i], t4, pm);
            }
            #pragma unroll
            for (int i = 0; i < 4; ++i) {
                rOld[i] = rCur[i];
                rCur[i] = nv[i];
                nxt[fbase + (1 + i) * EXTk] = nv[i];    // buffer row 4w+1+i
            }
            // Source injection (post-stencil, pre-recording).
            if (srcHere) {
                #pragma unroll
                for (int i = 0; i < 4; ++i) {
                    if (i == (exs & 3)) {
                        rCur[i] += sv[s];
                        nxt[(exs + 1) * EXTk + ezs] = rCur[i];
                    }
                }
            }
            __syncthreads();
            // Receiver sample of field@t0+s (post-injection). Next substep
            // writes the OTHER buffer -> race-free with one barrier.
            if (rOwn) rv[s] = nxt[rIdx];
        }

        // Store interior (ext rows 16..47 = waves 4..11, ez 16..47): agent
        // stores, visible to neighbors' agent loads without any fence.
        if (w >= 4 && w < 12 && ez >= TBk && ez < EXTk - TBk) {
            #pragma unroll
            for (int i = 0; i < 4; ++i)
                stg_f2(&Pout[pbase + i * PWk], make_float2(rCur[i], rOld[i]));
        }

        // Pre-publish barrier: every wave's vmcnt (agent-store acks) drained
        // before tid 0 issues the counter store. Also the block-internal
        // round serializer for the all-wave-poll scheme.
        __syncthreads();
        if (tid == 0)
            __hip_atomic_store(&done[myid], (unsigned)(k + 2),
                               __ATOMIC_RELAXED, __HIP_MEMORY_SCOPE_AGENT);

        // Receiver flush AFTER publish (block-private, off critical path).
        if (rOwn) {
            #pragma unroll
            for (int s = 0; s < TBk; ++s)
                out[tid * NSTEPSd + t0 + s] = rv[s];
        }
    }
}

extern "C" void kernel_launch(void* const* d_in, const int* in_sizes, int n_in,
                              void* d_out, int out_size, void* d_ws, size_t ws_size,
                              hipStream_t stream) {
    const float* vel    = (const float*)d_in[0];
    const float* source = (const float*)d_in[1];
    const int*   src_x  = (const int*)d_in[2];
    const int*   src_z  = (const int*)d_in[3];
    const int*   rec_x  = (const int*)d_in[4];
    const int*   rec_z  = (const int*)d_in[5];
    float* out = (float*)d_out;

    const size_t FP = (size_t)PWk * PWk;
    // Guard rows: [guard PWk][PA FP][PB FP][guard PWk][DONE]. PA's top OOB
    // (row -1) lands in the leading guard; PB's bottom OOB (row PWk) lands
    // in the trailing guard; PA-bottom/PB-top OOB land inside PB/PA.
    float2* base = (float2*)d_ws;
    float2* PA = base + PWk;
    float2* PB = PA + FP;
    unsigned* DONE = (unsigned*)(PB + FP + PWk);   // 256 counters, 128B stride

    hipMemsetAsync(DONE, 0, (size_t)NTILEk * NTILEk * 32 * sizeof(unsigned), stream);

    void* args[] = {(void*)&vel, (void*)&source, (void*)&src_x, (void*)&src_z,
                    (void*)&rec_x, (void*)&rec_z, (void*)&PA, (void*)&PB,
                    (void*)&out, (void*)&DONE};
    hipLaunchCooperativeKernel((void*)fdtd_persist, dim3(NTILEk, NTILEk),
                               dim3(1024), args, 0, stream);
}